// Round 5
// baseline (3674.147 us; speedup 1.0000x reference)
//
#include <hip/hip_runtime.h>
#include <math.h>

// Problem constants (from reference setup_inputs)
#define BB 16
#define DD 40
#define NN 64512
#define KK 4

#define ALPHA 5.0f
#define N_ITERS 10
#define EPS_KM 1e-9f

__device__ __forceinline__ void fma4s(float4& a, float s, const float4& v) {
    a.x = fmaf(s, v.x, a.x);
    a.y = fmaf(s, v.y, a.y);
    a.z = fmaf(s, v.z, a.z);
    a.w = fmaf(s, v.w, a.w);
}
__device__ __forceinline__ void fma4sq(float4& a, const float4& v) {
    a.x = fmaf(v.x, v.x, a.x);
    a.y = fmaf(v.y, v.y, a.y);
    a.z = fmaf(v.z, v.z, a.z);
    a.w = fmaf(v.w, v.w, a.w);
}
__device__ __forceinline__ float dot4acc(float acc, const float4& y, const float4& v) {
    return fmaf(y.x, v.x, fmaf(y.y, v.y, fmaf(y.z, v.z, fmaf(y.w, v.w, acc))));
}

// ===========================================================================
// PRIMARY PATH: transposed VactT[b][n][d] in workspace.
// ===========================================================================

// ---------------------------------------------------------------------------
// Kernel 1T: Vact = tanh(V) -> d_out [b][d][n]  AND  VactT -> ws [b][n][d].
// Thread = one point n: 40 coalesced scalar loads (256 B/wave-instr per d),
// 40 coalesced scalar stores ([d][n]), 10 dense float4 stores ([n][d]).
// grid (252, B) x 256.
// ---------------------------------------------------------------------------
__global__ __launch_bounds__(256) void tanh_t_kernel(const float* __restrict__ V,
                                                     float* __restrict__ Vact,
                                                     float* __restrict__ VactT) {
    const int tid = threadIdx.x;
    const int b = blockIdx.y;
    const int n = blockIdx.x * 256 + tid;

    const float* Vb = V + (size_t)b * (size_t)(DD * NN);
    float* Ob = Vact + (size_t)b * (size_t)(DD * NN);
    float4 buf[10];
    float* s = (float*)buf;
#pragma unroll
    for (int d = 0; d < DD; ++d) {
        const float x = tanhf(Vb[(size_t)d * NN + n]);
        Ob[(size_t)d * NN + n] = x;
        s[d] = x;
    }
    float4* T4 = (float4*)(VactT + (size_t)b * (size_t)(NN * DD) + (size_t)n * DD);
#pragma unroll
    for (int q = 0; q < 10; ++q) T4[q] = buf[q];
}

// ---------------------------------------------------------------------------
// Kernel 3T: one k-means iteration, thread-per-point on VactT.
// Block = 256 thr (4 waves), NPB=512 points.
// Phase 1: thread handles points nb+tid and nb+256+tid. 10 contiguous float4
//   loads per point; dist + softmax entirely in registers; y -> LDS yy[4][512];
//   per-wave butterfly of sum_y -> atomicAdd accS. No cross-lane in hot math.
// Phase 2 (one barrier): wave w owns d-slice [10w,10w+10); 8 steps of 64
//   points; 5 float2 loads/point (L2/L3-hot, just fetched); acc[4][10] in
//   registers; full-wave shfl_down reduce; lane0 does 40 atomicAdds.
// ---------------------------------------------------------------------------
#define NPB 512
#define GX (NN / NPB)  // 126

__global__ __launch_bounds__(256) void km_iter_t_kernel(const float* __restrict__ VactT,
                                                        const float* __restrict__ U,
                                                        const float* __restrict__ u2,
                                                        float* __restrict__ accV,
                                                        float* __restrict__ accS) {
    __shared__ float yy[KK][NPB];     // 8 KB
    __shared__ float sUd[DD * KK];    // [d][k], 640 B

    const int tid = threadIdx.x;
    const int w = tid >> 6;
    const int l = tid & 63;
    const int b = blockIdx.y;
    const int nb = blockIdx.x * NPB;

    const float* Tb = VactT + (size_t)b * (size_t)(NN * DD);

    if (tid < DD * KK) {
        const int d = tid >> 2;
        const int k = tid & 3;
        sUd[tid] = U[b * KK * DD + k * DD + d];
    }
    float u2r[KK];
#pragma unroll
    for (int k = 0; k < KK; ++k) u2r[k] = u2[b * KK + k];  // broadcast via cache
    __syncthreads();

    // ---------------- Phase 1: dist + softmax, thread-per-point --------------
    float sy[KK] = {0.f, 0.f, 0.f, 0.f};
#pragma unroll
    for (int h = 0; h < 2; ++h) {
        const int p = nb + h * 256 + tid;
        const float4* vp = (const float4*)(Tb + (size_t)p * DD);

        float pc0 = 0.f, pc1 = 0.f, pc2 = 0.f, pc3 = 0.f, pv = 0.f;
#pragma unroll
        for (int q = 0; q < 10; ++q) {
            const float4 v4 = vp[q];
#pragma unroll
            for (int e = 0; e < 4; ++e) {
                const float vv = (e == 0) ? v4.x : (e == 1) ? v4.y : (e == 2) ? v4.z : v4.w;
                const float4 u4 = *(const float4*)&sUd[(q * 4 + e) * 4];  // broadcast
                pv = fmaf(vv, vv, pv);
                pc0 = fmaf(u4.x, vv, pc0);
                pc1 = fmaf(u4.y, vv, pc1);
                pc2 = fmaf(u4.z, vv, pc2);
                pc3 = fmaf(u4.w, vv, pc3);
            }
        }
        const float cc[KK] = {pc0, pc1, pc2, pc3};
        float dist[KK];
        float m = -1e30f;
#pragma unroll
        for (int k = 0; k < KK; ++k) {
            const float d2 = fmaf(-2.f, cc[k], pv + u2r[k]);
            dist[k] = -ALPHA * sqrtf(fmaxf(d2, 1e-12f));
            m = fmaxf(m, dist[k]);
        }
        float e[KK];
        float se = 0.f;
#pragma unroll
        for (int k = 0; k < KK; ++k) {
            e[k] = expf(dist[k] - m);
            se += e[k];
        }
        const float inv = 1.f / se;
#pragma unroll
        for (int k = 0; k < KK; ++k) {
            const float y = e[k] * inv;
            yy[k][h * 256 + tid] = y;
            sy[k] += y;
        }
    }
#pragma unroll
    for (int k = 0; k < KK; ++k) {
        float sv = sy[k];
        for (int off = 32; off > 0; off >>= 1) sv += __shfl_down(sv, off, 64);
        if (l == 0) atomicAdd(&accS[b * KK + k], sv);
    }
    __syncthreads();

    // ---------------- Phase 2: accumulate y*v, wave-per-d-slice --------------
    const int d0 = w * 10;
    float acc[KK][10];
#pragma unroll
    for (int k = 0; k < KK; ++k)
#pragma unroll
        for (int j = 0; j < 10; ++j) acc[k][j] = 0.f;

#pragma unroll
    for (int s = 0; s < NPB / 64; ++s) {
        const int pl = s * 64 + l;
        const float2* vp = (const float2*)(Tb + (size_t)(nb + pl) * DD + d0);
        const float2 va = vp[0], vb2 = vp[1], vc = vp[2], vd = vp[3], ve = vp[4];
        const float vj[10] = {va.x, va.y, vb2.x, vb2.y, vc.x, vc.y, vd.x, vd.y, ve.x, ve.y};
        const float y0 = yy[0][pl];
        const float y1 = yy[1][pl];
        const float y2 = yy[2][pl];
        const float y3 = yy[3][pl];
#pragma unroll
        for (int j = 0; j < 10; ++j) {
            acc[0][j] = fmaf(y0, vj[j], acc[0][j]);
            acc[1][j] = fmaf(y1, vj[j], acc[1][j]);
            acc[2][j] = fmaf(y2, vj[j], acc[2][j]);
            acc[3][j] = fmaf(y3, vj[j], acc[3][j]);
        }
    }
#pragma unroll
    for (int k = 0; k < KK; ++k)
#pragma unroll
        for (int j = 0; j < 10; ++j) {
            float val = acc[k][j];
            for (int off = 32; off > 0; off >>= 1) val += __shfl_down(val, off, 64);
            if (l == 0) atomicAdd(&accV[b * KK * DD + k * DD + d0 + j], val);
        }
}

// ---------------------------------------------------------------------------
// Kernel 5T: mask = softmax_k(A . v), thread-per-point on VactT. grid (252,B).
// ---------------------------------------------------------------------------
__global__ __launch_bounds__(256) void mask_t_kernel(const float* __restrict__ VactT,
                                                     const float* __restrict__ U,
                                                     float* __restrict__ mask) {
    __shared__ float sA[KK * DD];
    const int tid = threadIdx.x;
    const int b = blockIdx.y;
    const int n = blockIdx.x * 256 + tid;

    for (int i = tid; i < KK * DD; i += 256) sA[i] = U[b * KK * DD + i];
    __syncthreads();

    const float4* vp = (const float4*)(VactT + (size_t)b * (size_t)(NN * DD) + (size_t)n * DD);
    float dk0 = 0.f, dk1 = 0.f, dk2 = 0.f, dk3 = 0.f;
#pragma unroll
    for (int q = 0; q < 10; ++q) {
        const float4 v4 = vp[q];
#pragma unroll
        for (int e = 0; e < 4; ++e) {
            const float vv = (e == 0) ? v4.x : (e == 1) ? v4.y : (e == 2) ? v4.z : v4.w;
            const int d = q * 4 + e;
            dk0 = fmaf(sA[0 * DD + d], vv, dk0);
            dk1 = fmaf(sA[1 * DD + d], vv, dk1);
            dk2 = fmaf(sA[2 * DD + d], vv, dk2);
            dk3 = fmaf(sA[3 * DD + d], vv, dk3);
        }
    }
    const float m = fmaxf(fmaxf(dk0, dk1), fmaxf(dk2, dk3));
    const float e0 = expf(dk0 - m), e1 = expf(dk1 - m), e2 = expf(dk2 - m), e3 = expf(dk3 - m);
    const float inv = 1.f / (e0 + e1 + e2 + e3);
    float* mb = mask + (size_t)b * (size_t)(KK * NN);
    mb[0 * NN + n] = e0 * inv;
    mb[1 * NN + n] = e1 * inv;
    mb[2 * NN + n] = e2 * inv;
    mb[3 * NN + n] = e3 * inv;
}

// ===========================================================================
// Shared kernels (both paths)
// ===========================================================================
__global__ __launch_bounds__(256) void init_kernel(const float* __restrict__ V,
                                                   const int* __restrict__ idx,
                                                   float* __restrict__ U,
                                                   float* __restrict__ accV,
                                                   float* __restrict__ accS,
                                                   float* __restrict__ u2) {
    const int tid = threadIdx.x;
    for (int i = tid; i < BB * KK * DD; i += 256) {
        int b = i / (KK * DD);
        int r = i - b * (KK * DD);
        int k = r / DD;
        int d = r - k * DD;
        int n0 = idx[b * KK + k];
        U[i] = tanhf(V[(size_t)(b * DD + d) * NN + n0]);
        accV[i] = 0.f;
    }
    __syncthreads();
    if (tid < BB * KK) {
        float s = 0.f;
        for (int d = 0; d < DD; ++d) {
            float x = U[tid * DD + d];
            s = fmaf(x, x, s);
        }
        u2[tid] = s;
        accS[tid] = 0.f;
    }
}

__global__ __launch_bounds__(256) void km_finalize_kernel(float* __restrict__ U,
                                                          float* __restrict__ accV,
                                                          float* __restrict__ accS,
                                                          float* __restrict__ u2) {
    const int tid = threadIdx.x;
    for (int i = tid; i < BB * KK * DD; i += 256) {
        U[i] = accV[i] / (accS[i / DD] + EPS_KM);
        accV[i] = 0.f;
    }
    __syncthreads();
    if (tid < BB * KK) {
        float s = 0.f;
        for (int d = 0; d < DD; ++d) {
            float x = U[tid * DD + d];
            s = fmaf(x, x, s);
        }
        u2[tid] = s;
        accS[tid] = 0.f;
    }
}

__global__ __launch_bounds__(256) void copyA_kernel(const float* __restrict__ U,
                                                    float* __restrict__ Aout) {
    int i = blockIdx.x * 256 + threadIdx.x;
    if (i < BB * KK * DD) Aout[i] = U[i];
}

// ===========================================================================
// FALLBACK PATH (ws too small): round-3 kernels reading [d][n] Vact in d_out.
// ===========================================================================
__global__ __launch_bounds__(256) void tanh_kernel(const float4* __restrict__ V,
                                                   float4* __restrict__ Vact,
                                                   int n4) {
    int i = blockIdx.x * 256 + threadIdx.x;
    if (i < n4) {
        float4 x = V[i];
        float4 y;
        y.x = tanhf(x.x);
        y.y = tanhf(x.y);
        y.z = tanhf(x.z);
        y.w = tanhf(x.w);
        Vact[i] = y;
    }
}

__global__ __launch_bounds__(256) void km_iter_dn_kernel(const float* __restrict__ Vact,
                                                         const float* __restrict__ U,
                                                         const float* __restrict__ u2,
                                                         float* __restrict__ accV,
                                                         float* __restrict__ accS) {
    __shared__ float smem[24 * NPB + 192];
    float (*pp)[NPB] = (float (*)[NPB])smem;
    float (*yy)[NPB] = (float (*)[NPB])(smem + 20 * NPB);
    float* sUd = smem + 24 * NPB;

    const int tid = threadIdx.x;
    const int w = tid >> 6;
    const int l = tid & 63;
    const int b = blockIdx.y;
    const int d0 = w * 10;
    const int nb = blockIdx.x * NPB;

    const float* Vb = Vact + (size_t)b * (size_t)(DD * NN);
    const float* Ub = U + b * (KK * DD);

    if (tid < KK * DD) {
        const int d = tid >> 2;
        const int k = tid & 3;
        sUd[tid] = Ub[k * DD + d];
    }
    __syncthreads();

#pragma unroll
    for (int s = 0; s < NPB / 256; ++s) {
        const int p0 = s * 256 + 4 * l;
        float4 v[10];
#pragma unroll
        for (int j = 0; j < 10; ++j)
            v[j] = *(const float4*)(Vb + (size_t)(d0 + j) * NN + nb + p0);

        float4 c0 = {0,0,0,0}, c1 = {0,0,0,0}, c2 = {0,0,0,0}, c3 = {0,0,0,0};
        float4 q = {0,0,0,0};
#pragma unroll
        for (int j = 0; j < 10; ++j) {
            const float4 u4 = *(const float4*)&sUd[(d0 + j) * 4];
            fma4sq(q, v[j]);
            fma4s(c0, u4.x, v[j]);
            fma4s(c1, u4.y, v[j]);
            fma4s(c2, u4.z, v[j]);
            fma4s(c3, u4.w, v[j]);
        }
        *(float4*)&pp[w * 5 + 0][p0] = c0;
        *(float4*)&pp[w * 5 + 1][p0] = c1;
        *(float4*)&pp[w * 5 + 2][p0] = c2;
        *(float4*)&pp[w * 5 + 3][p0] = c3;
        *(float4*)&pp[w * 5 + 4][p0] = q;
    }
    __syncthreads();

    float u2r[KK];
#pragma unroll
    for (int k = 0; k < KK; ++k) u2r[k] = u2[b * KK + k];

    float sy[KK] = {0.f, 0.f, 0.f, 0.f};
#pragma unroll
    for (int s2 = 0; s2 < NPB / 256; ++s2) {
        const int nl = w * (NPB / 4) + s2 * 64 + l;
        float cc[KK];
#pragma unroll
        for (int k = 0; k < KK; ++k)
            cc[k] = pp[k][nl] + pp[5 + k][nl] + pp[10 + k][nl] + pp[15 + k][nl];
        const float v2 = pp[4][nl] + pp[9][nl] + pp[14][nl] + pp[19][nl];

        float dist[KK];
        float m = -1e30f;
#pragma unroll
        for (int k = 0; k < KK; ++k) {
            float d2 = fmaf(-2.f, cc[k], v2 + u2r[k]);
            dist[k] = -ALPHA * sqrtf(fmaxf(d2, 1e-12f));
            m = fmaxf(m, dist[k]);
        }
        float e[KK];
        float se = 0.f;
#pragma unroll
        for (int k = 0; k < KK; ++k) {
            e[k] = expf(dist[k] - m);
            se += e[k];
        }
        const float inv = 1.f / se;
#pragma unroll
        for (int k = 0; k < KK; ++k) {
            const float y = e[k] * inv;
            yy[k][nl] = y;
            sy[k] += y;
        }
    }
#pragma unroll
    for (int k = 0; k < KK; ++k) {
        float sv = sy[k];
        for (int off = 32; off > 0; off >>= 1) sv += __shfl_down(sv, off, 64);
        if (l == 0) atomicAdd(&accS[b * KK + k], sv);
    }
    __syncthreads();

    float acc[KK][10];
#pragma unroll
    for (int k = 0; k < KK; ++k)
#pragma unroll
        for (int j = 0; j < 10; ++j) acc[k][j] = 0.f;

#pragma unroll
    for (int s = 0; s < NPB / 256; ++s) {
        const int p0 = s * 256 + 4 * l;
        float4 v[10];
#pragma unroll
        for (int j = 0; j < 10; ++j)
            v[j] = *(const float4*)(Vb + (size_t)(d0 + j) * NN + nb + p0);
        const float4 y0 = *(const float4*)&yy[0][p0];
        const float4 y1 = *(const float4*)&yy[1][p0];
        const float4 y2 = *(const float4*)&yy[2][p0];
        const float4 y3 = *(const float4*)&yy[3][p0];
#pragma unroll
        for (int j = 0; j < 10; ++j) {
            acc[0][j] = dot4acc(acc[0][j], y0, v[j]);
            acc[1][j] = dot4acc(acc[1][j], y1, v[j]);
            acc[2][j] = dot4acc(acc[2][j], y2, v[j]);
            acc[3][j] = dot4acc(acc[3][j], y3, v[j]);
        }
    }
#pragma unroll
    for (int k = 0; k < KK; ++k)
#pragma unroll
        for (int j = 0; j < 10; ++j) {
            float val = acc[k][j];
            for (int off = 32; off > 0; off >>= 1) val += __shfl_down(val, off, 64);
            if (l == 0) atomicAdd(&accV[b * KK * DD + k * DD + d0 + j], val);
        }
}

__global__ __launch_bounds__(256) void mask_dn_kernel(const float* __restrict__ Vact,
                                                      const float* __restrict__ U,
                                                      float* __restrict__ mask) {
    __shared__ float sA[KK * DD];
    const int tid = threadIdx.x;
    const int b = blockIdx.y;
    const int n0 = blockIdx.x * 1024 + 4 * tid;

    for (int i = tid; i < KK * DD; i += 256) sA[i] = U[b * KK * DD + i];
    __syncthreads();

    const float* Vb = Vact + (size_t)b * (size_t)(DD * NN);
    float4 dk0 = {0,0,0,0}, dk1 = {0,0,0,0}, dk2 = {0,0,0,0}, dk3 = {0,0,0,0};
    for (int d = 0; d < DD; ++d) {
        const float4 vv = *(const float4*)(Vb + (size_t)d * NN + n0);
        fma4s(dk0, sA[0 * DD + d], vv);
        fma4s(dk1, sA[1 * DD + d], vv);
        fma4s(dk2, sA[2 * DD + d], vv);
        fma4s(dk3, sA[3 * DD + d], vv);
    }
    float4 m;
    m.x = fmaxf(fmaxf(dk0.x, dk1.x), fmaxf(dk2.x, dk3.x));
    m.y = fmaxf(fmaxf(dk0.y, dk1.y), fmaxf(dk2.y, dk3.y));
    m.z = fmaxf(fmaxf(dk0.z, dk1.z), fmaxf(dk2.z, dk3.z));
    m.w = fmaxf(fmaxf(dk0.w, dk1.w), fmaxf(dk2.w, dk3.w));
    float4 e0, e1, e2, e3, inv;
    e0.x = expf(dk0.x - m.x); e0.y = expf(dk0.y - m.y); e0.z = expf(dk0.z - m.z); e0.w = expf(dk0.w - m.w);
    e1.x = expf(dk1.x - m.x); e1.y = expf(dk1.y - m.y); e1.z = expf(dk1.z - m.z); e1.w = expf(dk1.w - m.w);
    e2.x = expf(dk2.x - m.x); e2.y = expf(dk2.y - m.y); e2.z = expf(dk2.z - m.z); e2.w = expf(dk2.w - m.w);
    e3.x = expf(dk3.x - m.x); e3.y = expf(dk3.y - m.y); e3.z = expf(dk3.z - m.z); e3.w = expf(dk3.w - m.w);
    inv.x = 1.f / (e0.x + e1.x + e2.x + e3.x);
    inv.y = 1.f / (e0.y + e1.y + e2.y + e3.y);
    inv.z = 1.f / (e0.z + e1.z + e2.z + e3.z);
    inv.w = 1.f / (e0.w + e1.w + e2.w + e3.w);
    e0.x *= inv.x; e0.y *= inv.y; e0.z *= inv.z; e0.w *= inv.w;
    e1.x *= inv.x; e1.y *= inv.y; e1.z *= inv.z; e1.w *= inv.w;
    e2.x *= inv.x; e2.y *= inv.y; e2.z *= inv.z; e2.w *= inv.w;
    e3.x *= inv.x; e3.y *= inv.y; e3.z *= inv.z; e3.w *= inv.w;
    float* mb = mask + (size_t)b * (size_t)(KK * NN);
    *(float4*)(mb + 0 * NN + n0) = e0;
    *(float4*)(mb + 1 * NN + n0) = e1;
    *(float4*)(mb + 2 * NN + n0) = e2;
    *(float4*)(mb + 3 * NN + n0) = e3;
}

// ---------------------------------------------------------------------------
extern "C" void kernel_launch(void* const* d_in, const int* in_sizes, int n_in,
                              void* d_out, int out_size, void* d_ws, size_t ws_size,
                              hipStream_t stream) {
    const float* V = (const float*)d_in[0];
    const int* idx = (const int*)d_in[1];

    float* out = (float*)d_out;
    float* mask = out;                                   // B*K*N
    float* Vact = out + (size_t)BB * KK * NN;            // B*D*N
    float* Aout = Vact + (size_t)BB * DD * NN;           // B*K*D

    float* ws = (float*)d_ws;
    float* U    = ws;            // 2560
    float* accV = ws + 2560;     // 2560
    float* accS = ws + 5120;     // 64
    float* u2   = ws + 5184;     // 64
    float* VactT = ws + 8192;    // B*N*D floats (165 MB) if ws_size permits

    const size_t needT = (size_t)8192 * 4 + (size_t)BB * NN * DD * 4;
    const bool useT = (ws_size >= needT);

    init_kernel<<<dim3(1), dim3(256), 0, stream>>>(V, idx, U, accV, accS, u2);

    if (useT) {
        tanh_t_kernel<<<dim3(NN / 256, BB), dim3(256), 0, stream>>>(V, Vact, VactT);
        for (int it = 0; it < N_ITERS; ++it) {
            km_iter_t_kernel<<<dim3(GX, BB), dim3(256), 0, stream>>>(VactT, U, u2, accV, accS);
            km_finalize_kernel<<<dim3(1), dim3(256), 0, stream>>>(U, accV, accS, u2);
        }
        mask_t_kernel<<<dim3(NN / 256, BB), dim3(256), 0, stream>>>(VactT, U, mask);
    } else {
        const int n4 = (BB * DD * NN) / 4;
        tanh_kernel<<<dim3((n4 + 255) / 256), dim3(256), 0, stream>>>(
            (const float4*)V, (float4*)Vact, n4);
        for (int it = 0; it < N_ITERS; ++it) {
            km_iter_dn_kernel<<<dim3(GX, BB), dim3(256), 0, stream>>>(Vact, U, u2, accV, accS);
            km_finalize_kernel<<<dim3(1), dim3(256), 0, stream>>>(U, accV, accS, u2);
        }
        mask_dn_kernel<<<dim3(NN / 1024, BB), dim3(256), 0, stream>>>(Vact, U, mask);
    }
    copyA_kernel<<<dim3(10), dim3(256), 0, stream>>>(U, Aout);
}